// Round 18
// baseline (108.414 us; speedup 1.0000x reference)
//
#include <hip/hip_runtime.h>
#include <hip/hip_fp16.h>

#define SQRT3 1.7320508075688772f
#define INV_SQRT3 0.5773502691896258f
#define CAP 64

#define WAVE_SYNC() do { asm volatile("s_waitcnt lgkmcnt(0)" ::: "memory"); \
                         __builtin_amdgcn_wave_barrier(); } while (0)

typedef _Float16 h2v __attribute__((ext_vector_type(2)));
static __device__ __forceinline__ h2v uint_as_h2(unsigned u) {
    union { unsigned u; h2v h; } c; c.u = u; return c.h;
}
static __device__ __forceinline__ unsigned pack_h2(float a, float b) {
    __half2 t = __floats2half2_rn(a, b);
    return *(const unsigned*)&t;
}

// ---------------- fused prep: featH(f16) + pos4 + folded h2-packed weights + cnt=0 ----
// featH[node*32+cl] = half4{s_cl, v_cl0, v_cl1, v_cl2}  (256 B per node, contiguous)
// WS2[u2*32+j] = h2{fs(2u2,j), fs(2u2+1,j)};  WV2 likewise (all scales folded)
__global__ void prep_kernel(const float* __restrict__ feat, const float* __restrict__ pos,
                            const float* __restrict__ Ws, const float* __restrict__ Wv,
                            const float* __restrict__ tpw,
                            uint2* __restrict__ featH, float4* __restrict__ pos4,
                            int* __restrict__ cnt,
                            unsigned* __restrict__ WS2, unsigned* __restrict__ WV2, int N) {
    int i = blockIdx.x * blockDim.x + threadIdx.x;
    int totalF = N * 32;
    if (i < totalF) {
        int node = i >> 5, cl = i & 31;
        const float* fb = feat + (size_t)node * 128;
        float s  = fb[cl];
        float v0 = fb[32 + 3 * cl], v1 = fb[33 + 3 * cl], v2 = fb[34 + 3 * cl];
        uint2 r;
        r.x = pack_h2(s, v0);
        r.y = pack_h2(v1, v2);
        featH[i] = r;
        return;
    }
    int j = i - totalF;
    if (j < N) {
        pos4[j] = make_float4(pos[3 * j], pos[3 * j + 1], pos[3 * j + 2], 0.f);
        cnt[j] = 0;                        // zero scatter cursors (no memset pass)
        return;
    }
    int k = j - N;
    if (k < 1024) {                        // u2 = k>>5 in [0,32), col = k&31
        int u2 = k >> 5, c = k & 31;
        int ua = 2 * u2, ub = 2 * u2 + 1;
        auto fs = [&](int u) {
            float w = Ws[u * 32 + c];
            return (u < 32) ? 0.125f * tpw[u] * w
                            : 0.125f * tpw[96 + (u - 32)] * INV_SQRT3 * w;
        };
        auto fv = [&](int u) {
            float w = Wv[u * 32 + c];
            return (u < 32) ? 0.125f * tpw[32 + u] * w
                            : 0.125f * tpw[64 + (u - 32)] * w;
        };
        WS2[k] = pack_h2(fs(ua), fs(ub));
        WV2[k] = pack_h2(fv(ua), fv(ub));
    }
}

// ---------------- single-pass padded-CSR scatter: 1 edge/thread (proven R17) --------
__global__ void scatter_kernel(const int* __restrict__ esrc, const int* __restrict__ edst,
                               int* __restrict__ cnt, int* __restrict__ csrP, int E) {
    int e = blockIdx.x * blockDim.x + threadIdx.x;
    if (e < E) {
        int s = esrc[e];
        int d = edst[e];
        int p = atomicAdd(&cnt[d], 1);
        if (p < CAP) csrP[(size_t)d * CAP + p] = s;
    }
}

// ---------------- per-node gather + TP + linear (R15 loop + fdot2 epilogue) ---------
// 1 wave/node, HALF-wave per edge, lane owns channel cl = {s,v0,v1,v2} (f16x4, 8B).
// Aggregates packed to h2 pairs along u in LDS; epilogue = 32 v_dot2_f32_f16 per
// output (no cvt, half the FMA issue of the f32 epilogue).

__global__ __launch_bounds__(256) void node_kernel(
    const uint2* __restrict__ featH, const float4* __restrict__ pos4,
    const int* __restrict__ csrP, const int* __restrict__ cnt,
    const unsigned* __restrict__ WS2, const unsigned* __restrict__ WV2,
    float* __restrict__ out, int N)
{
    __shared__ float4 geom[4][64];
    __shared__ __align__(16) unsigned hS[4][36], hX[4][36], hY[4][36], hZ[4][36];
    int lane = threadIdx.x & 63;
    int w    = threadIdx.x >> 6;
    int node = blockIdx.x * 4 + w;
    if (node >= N) return;                 // whole-wave exit; no block barriers used

    int deg = cnt[node];                   // cursor after scatter == degree
    int len = deg < CAP ? deg : CAP;
    int half = lane >> 5;
    int cl   = lane & 31;

    float4 pd = pos4[node];                // wave-uniform

    if (lane < len) {
        int s = csrP[(size_t)node * CAP + lane];
        float4 ps = pos4[s];
        float ex = pd.x - ps.x, ey = pd.y - ps.y, ez = pd.z - ps.z;
        float rr = SQRT3 * rsqrtf(ex * ex + ey * ey + ez * ez + 1e-12f);
        geom[w][lane] = make_float4(rr * ex, rr * ey, rr * ez, __int_as_float(s));
    }
    WAVE_SYNC();

    float A0 = 0.f, A1x = 0.f, A1y = 0.f, A1z = 0.f;   // s-channel cl: a0, a1
    float V0 = 0.f, V1 = 0.f, V2 = 0.f, T3 = 0.f;      // v-channel cl: a2, a3(raw)

    int even = len & ~1;
    #pragma unroll 4
    for (int m = 0; m < even; m += 2) {
        float4 g = geom[w][m + half];
        int si = __float_as_int(g.w);
        uint2 fr = featH[(size_t)si * 32 + cl];
        float2 lo = __half22float2(*(const __half2*)&fr.x);   // {s, v0}
        float2 hi = __half22float2(*(const __half2*)&fr.y);   // {v1, v2}
        A0 += lo.x;
        A1x = fmaf(lo.x, g.x, A1x); A1y = fmaf(lo.x, g.y, A1y); A1z = fmaf(lo.x, g.z, A1z);
        V0 += lo.y; V1 += hi.x; V2 += hi.y;
        T3 = fmaf(lo.y, g.x, fmaf(hi.x, g.y, fmaf(hi.y, g.z, T3)));
    }
    if (len & 1) {                         // odd tail: half 0 only
        if (half == 0) {
            float4 g = geom[w][len - 1];
            int si = __float_as_int(g.w);
            uint2 fr = featH[(size_t)si * 32 + cl];
            float2 lo = __half22float2(*(const __half2*)&fr.x);
            float2 hi = __half22float2(*(const __half2*)&fr.y);
            A0 += lo.x;
            A1x = fmaf(lo.x, g.x, A1x); A1y = fmaf(lo.x, g.y, A1y); A1z = fmaf(lo.x, g.z, A1z);
            V0 += lo.y; V1 += hi.x; V2 += hi.y;
            T3 = fmaf(lo.y, g.x, fmaf(hi.x, g.y, fmaf(hi.y, g.z, T3)));
        }
    }

    // cross-half reduce (lanes L, L+32 hold same channel over disjoint edges)
    A0 += __shfl_xor(A0, 32);  A1x += __shfl_xor(A1x, 32);
    A1y += __shfl_xor(A1y, 32); A1z += __shfl_xor(A1z, 32);
    V0 += __shfl_xor(V0, 32);  V1 += __shfl_xor(V1, 32);
    V2 += __shfl_xor(V2, 32);  T3 += __shfl_xor(T3, 32);

    // pack h2 pairs along u: lane holds u=cl value; neighbor (cl^1) gives the pair.
    // layout (entries of 32 h2): [0,16)=s-path raw {A0|A1x/y/z}, [16,32)={T3|V0/1/2}
    {
        float q0 = half ? T3 : A0;
        float q1 = half ? V0 : A1x;
        float q2 = half ? V1 : A1y;
        float q3 = half ? V2 : A1z;
        float p0 = __shfl_xor(q0, 1);
        float p1 = __shfl_xor(q1, 1);
        float p2 = __shfl_xor(q2, 1);
        float p3 = __shfl_xor(q3, 1);
        if (!(lane & 1)) {                 // even lane: (q,p) = (u=cl, u=cl+1)
            int k2 = (half ? 16 : 0) + (cl >> 1);
            hS[w][k2] = pack_h2(q0, p0);
            hX[w][k2] = pack_h2(q1, p1);
            hY[w][k2] = pack_h2(q2, p2);
            hZ[w][k2] = pack_h2(q3, p3);
        }
    }
    WAVE_SYNC();

    // epilogue: outputs j = lane, lane+64; 32 fdot2 per output, weights lane-coalesced
    size_t ob = (size_t)node * 128;
    #pragma unroll
    for (int t = 0; t < 2; ++t) {
        int j = lane + 64 * t;
        const uint4* ap4;
        const unsigned* wpu;
        if (j < 32) {
            ap4 = (const uint4*)&hS[w][0]; wpu = WS2 + j;
        } else {
            int v = j - 32;
            int o = v / 3, mm = v - 3 * o;
            ap4 = (const uint4*)((mm == 0) ? &hX[w][0] : (mm == 1) ? &hY[w][0] : &hZ[w][0]);
            wpu = WV2 + o;
        }
        float r = 0.f;
        #pragma unroll
        for (int q8 = 0; q8 < 8; ++q8) {
            uint4 a4 = ap4[q8];
            r = __builtin_amdgcn_fdot2(uint_as_h2(a4.x), uint_as_h2(wpu[(4 * q8 + 0) * 32]), r, false);
            r = __builtin_amdgcn_fdot2(uint_as_h2(a4.y), uint_as_h2(wpu[(4 * q8 + 1) * 32]), r, false);
            r = __builtin_amdgcn_fdot2(uint_as_h2(a4.z), uint_as_h2(wpu[(4 * q8 + 2) * 32]), r, false);
            r = __builtin_amdgcn_fdot2(uint_as_h2(a4.w), uint_as_h2(wpu[(4 * q8 + 3) * 32]), r, false);
        }
        out[ob + j] = r;                   // all scales folded into WS2/WV2
    }
}

extern "C" void kernel_launch(void* const* d_in, const int* in_sizes, int n_in,
                              void* d_out, int out_size, void* d_ws, size_t ws_size,
                              hipStream_t stream) {
    const float* feat = (const float*)d_in[0];
    const float* pos  = (const float*)d_in[1];
    const int*   esrc = (const int*)d_in[2];
    const int*   edst = (const int*)d_in[3];
    const float* tpw  = (const float*)d_in[4];
    const float* Ws   = (const float*)d_in[5];
    const float* Wv   = (const float*)d_in[6];
    float* out = (float*)d_out;

    int N = in_sizes[0] / 128;
    int E = in_sizes[2];

    uint2*    featH = (uint2*)d_ws;                      // N*32   (12.8 MB, 256 B/node)
    float4*   pos4  = (float4*)(featH + (size_t)N * 32); // N      (0.8 MB)
    int*      csrP  = (int*)(pos4 + N);                  // N*CAP  (12.8 MB)
    int*      cnt   = csrP + (size_t)N * CAP;            // N      (0.2 MB)
    unsigned* WS2   = (unsigned*)(cnt + N);              // 1024   (4 KB)
    unsigned* WV2   = WS2 + 1024;                        // 1024   (4 KB)

    const int tb = 256;
    int prepTot = N * 32 + N + 1024;
    prep_kernel<<<(prepTot + tb - 1) / tb, tb, 0, stream>>>(feat, pos, Ws, Wv, tpw,
                                                            featH, pos4, cnt, WS2, WV2, N);
    scatter_kernel<<<(E + tb - 1) / tb, tb, 0, stream>>>(esrc, edst, cnt, csrP, E);
    node_kernel<<<(N + 3) / 4, 256, 0, stream>>>(featH, pos4, csrP, cnt, WS2, WV2, out, N);
}

// Round 19
// 107.030 us; speedup vs baseline: 1.0129x; 1.0129x over previous
//
#include <hip/hip_runtime.h>
#include <hip/hip_fp16.h>

#define SQRT3 1.7320508075688772f
#define INV_SQRT3 0.5773502691896258f
#define CAP 64

#define WAVE_SYNC() do { asm volatile("s_waitcnt lgkmcnt(0)" ::: "memory"); \
                         __builtin_amdgcn_wave_barrier(); } while (0)

typedef _Float16 h2v __attribute__((ext_vector_type(2)));
static __device__ __forceinline__ h2v uint_as_h2(unsigned u) {
    union { unsigned u; h2v h; } c; c.u = u; return c.h;
}
static __device__ __forceinline__ unsigned pack_h2(float a, float b) {
    __half2 t = __floats2half2_rn(a, b);
    return *(const unsigned*)&t;
}

// ---------------- fused build: scatter (blocks [0,sblocks)) + prep (rest) ----------
// scatter: 1 edge/thread; p = atomicAdd(&cnt[d],1); csrP[d*CAP+p] = s. cnt pre-zeroed
//          by hipMemsetAsync. Afterwards cnt[d] == degree(d).
// prep:    featH[node*32+cl] = half4{s_cl, v_cl0, v_cl1, v_cl2} (256 B/node);
//          pos4; WS2/WV2 h2-packed folded weights (all scales folded).
// The two parts touch disjoint data; scatter's atomic-latency waves overlap prep's
// streaming work on the same CUs.
__global__ void build_kernel(const int* __restrict__ esrc, const int* __restrict__ edst,
                             const float* __restrict__ feat, const float* __restrict__ pos,
                             const float* __restrict__ Ws, const float* __restrict__ Wv,
                             const float* __restrict__ tpw,
                             int* __restrict__ cnt, int* __restrict__ csrP,
                             uint2* __restrict__ featH, float4* __restrict__ pos4,
                             unsigned* __restrict__ WS2, unsigned* __restrict__ WV2,
                             int N, int E, int sblocks) {
    int b = blockIdx.x;
    if (b < sblocks) {                     // ---- scatter part ----
        int e = b * blockDim.x + threadIdx.x;
        if (e < E) {
            int s = esrc[e];
            int d = edst[e];
            int p = atomicAdd(&cnt[d], 1);
            if (p < CAP) csrP[(size_t)d * CAP + p] = s;
        }
        return;
    }
    // ---- prep part ----
    int i = (b - sblocks) * blockDim.x + threadIdx.x;
    int totalF = N * 32;
    if (i < totalF) {
        int node = i >> 5, cl = i & 31;
        const float* fb = feat + (size_t)node * 128;
        float s  = fb[cl];
        float v0 = fb[32 + 3 * cl], v1 = fb[33 + 3 * cl], v2 = fb[34 + 3 * cl];
        uint2 r;
        r.x = pack_h2(s, v0);
        r.y = pack_h2(v1, v2);
        featH[i] = r;
        return;
    }
    int j = i - totalF;
    if (j < N) {
        pos4[j] = make_float4(pos[3 * j], pos[3 * j + 1], pos[3 * j + 2], 0.f);
        return;
    }
    int k = j - N;
    if (k < 1024) {                        // u2 = k>>5 in [0,32), col = k&31
        int u2 = k >> 5, c = k & 31;
        int ua = 2 * u2, ub = 2 * u2 + 1;
        auto fs = [&](int u) {
            float w = Ws[u * 32 + c];
            return (u < 32) ? 0.125f * tpw[u] * w
                            : 0.125f * tpw[96 + (u - 32)] * INV_SQRT3 * w;
        };
        auto fv = [&](int u) {
            float w = Wv[u * 32 + c];
            return (u < 32) ? 0.125f * tpw[32 + u] * w
                            : 0.125f * tpw[64 + (u - 32)] * w;
        };
        WS2[k] = pack_h2(fs(ua), fs(ub));
        WV2[k] = pack_h2(fv(ua), fv(ub));
    }
}

// ---------------- per-node gather + TP + linear (EXACT R18: R15 loop + fdot2) -------
// 1 wave/node, HALF-wave per edge, lane owns channel cl = {s,v0,v1,v2} (f16x4, 8B).
// Aggregates packed to h2 pairs along u in LDS; epilogue = 32 v_dot2_f32_f16 per
// output (no cvt, half the FMA issue of the f32 epilogue).

__global__ __launch_bounds__(256) void node_kernel(
    const uint2* __restrict__ featH, const float4* __restrict__ pos4,
    const int* __restrict__ csrP, const int* __restrict__ cnt,
    const unsigned* __restrict__ WS2, const unsigned* __restrict__ WV2,
    float* __restrict__ out, int N)
{
    __shared__ float4 geom[4][64];
    __shared__ __align__(16) unsigned hS[4][36], hX[4][36], hY[4][36], hZ[4][36];
    int lane = threadIdx.x & 63;
    int w    = threadIdx.x >> 6;
    int node = blockIdx.x * 4 + w;
    if (node >= N) return;                 // whole-wave exit; no block barriers used

    int deg = cnt[node];                   // cursor after scatter == degree
    int len = deg < CAP ? deg : CAP;
    int half = lane >> 5;
    int cl   = lane & 31;

    float4 pd = pos4[node];                // wave-uniform

    if (lane < len) {
        int s = csrP[(size_t)node * CAP + lane];
        float4 ps = pos4[s];
        float ex = pd.x - ps.x, ey = pd.y - ps.y, ez = pd.z - ps.z;
        float rr = SQRT3 * rsqrtf(ex * ex + ey * ey + ez * ez + 1e-12f);
        geom[w][lane] = make_float4(rr * ex, rr * ey, rr * ez, __int_as_float(s));
    }
    WAVE_SYNC();

    float A0 = 0.f, A1x = 0.f, A1y = 0.f, A1z = 0.f;   // s-channel cl: a0, a1
    float V0 = 0.f, V1 = 0.f, V2 = 0.f, T3 = 0.f;      // v-channel cl: a2, a3(raw)

    int even = len & ~1;
    #pragma unroll 4
    for (int m = 0; m < even; m += 2) {
        float4 g = geom[w][m + half];
        int si = __float_as_int(g.w);
        uint2 fr = featH[(size_t)si * 32 + cl];
        float2 lo = __half22float2(*(const __half2*)&fr.x);   // {s, v0}
        float2 hi = __half22float2(*(const __half2*)&fr.y);   // {v1, v2}
        A0 += lo.x;
        A1x = fmaf(lo.x, g.x, A1x); A1y = fmaf(lo.x, g.y, A1y); A1z = fmaf(lo.x, g.z, A1z);
        V0 += lo.y; V1 += hi.x; V2 += hi.y;
        T3 = fmaf(lo.y, g.x, fmaf(hi.x, g.y, fmaf(hi.y, g.z, T3)));
    }
    if (len & 1) {                         // odd tail: half 0 only
        if (half == 0) {
            float4 g = geom[w][len - 1];
            int si = __float_as_int(g.w);
            uint2 fr = featH[(size_t)si * 32 + cl];
            float2 lo = __half22float2(*(const __half2*)&fr.x);
            float2 hi = __half22float2(*(const __half2*)&fr.y);
            A0 += lo.x;
            A1x = fmaf(lo.x, g.x, A1x); A1y = fmaf(lo.x, g.y, A1y); A1z = fmaf(lo.x, g.z, A1z);
            V0 += lo.y; V1 += hi.x; V2 += hi.y;
            T3 = fmaf(lo.y, g.x, fmaf(hi.x, g.y, fmaf(hi.y, g.z, T3)));
        }
    }

    // cross-half reduce (lanes L, L+32 hold same channel over disjoint edges)
    A0 += __shfl_xor(A0, 32);  A1x += __shfl_xor(A1x, 32);
    A1y += __shfl_xor(A1y, 32); A1z += __shfl_xor(A1z, 32);
    V0 += __shfl_xor(V0, 32);  V1 += __shfl_xor(V1, 32);
    V2 += __shfl_xor(V2, 32);  T3 += __shfl_xor(T3, 32);

    // pack h2 pairs along u: lane holds u=cl value; neighbor (cl^1) gives the pair.
    // layout (entries of 32 h2): [0,16)=s-path raw {A0|A1x/y/z}, [16,32)={T3|V0/1/2}
    {
        float q0 = half ? T3 : A0;
        float q1 = half ? V0 : A1x;
        float q2 = half ? V1 : A1y;
        float q3 = half ? V2 : A1z;
        float p0 = __shfl_xor(q0, 1);
        float p1 = __shfl_xor(q1, 1);
        float p2 = __shfl_xor(q2, 1);
        float p3 = __shfl_xor(q3, 1);
        if (!(lane & 1)) {                 // even lane: (q,p) = (u=cl, u=cl+1)
            int k2 = (half ? 16 : 0) + (cl >> 1);
            hS[w][k2] = pack_h2(q0, p0);
            hX[w][k2] = pack_h2(q1, p1);
            hY[w][k2] = pack_h2(q2, p2);
            hZ[w][k2] = pack_h2(q3, p3);
        }
    }
    WAVE_SYNC();

    // epilogue: outputs j = lane, lane+64; 32 fdot2 per output, weights lane-coalesced
    size_t ob = (size_t)node * 128;
    #pragma unroll
    for (int t = 0; t < 2; ++t) {
        int j = lane + 64 * t;
        const uint4* ap4;
        const unsigned* wpu;
        if (j < 32) {
            ap4 = (const uint4*)&hS[w][0]; wpu = WS2 + j;
        } else {
            int v = j - 32;
            int o = v / 3, mm = v - 3 * o;
            ap4 = (const uint4*)((mm == 0) ? &hX[w][0] : (mm == 1) ? &hY[w][0] : &hZ[w][0]);
            wpu = WV2 + o;
        }
        float r = 0.f;
        #pragma unroll
        for (int q8 = 0; q8 < 8; ++q8) {
            uint4 a4 = ap4[q8];
            r = __builtin_amdgcn_fdot2(uint_as_h2(a4.x), uint_as_h2(wpu[(4 * q8 + 0) * 32]), r, false);
            r = __builtin_amdgcn_fdot2(uint_as_h2(a4.y), uint_as_h2(wpu[(4 * q8 + 1) * 32]), r, false);
            r = __builtin_amdgcn_fdot2(uint_as_h2(a4.z), uint_as_h2(wpu[(4 * q8 + 2) * 32]), r, false);
            r = __builtin_amdgcn_fdot2(uint_as_h2(a4.w), uint_as_h2(wpu[(4 * q8 + 3) * 32]), r, false);
        }
        out[ob + j] = r;                   // all scales folded into WS2/WV2
    }
}

extern "C" void kernel_launch(void* const* d_in, const int* in_sizes, int n_in,
                              void* d_out, int out_size, void* d_ws, size_t ws_size,
                              hipStream_t stream) {
    const float* feat = (const float*)d_in[0];
    const float* pos  = (const float*)d_in[1];
    const int*   esrc = (const int*)d_in[2];
    const int*   edst = (const int*)d_in[3];
    const float* tpw  = (const float*)d_in[4];
    const float* Ws   = (const float*)d_in[5];
    const float* Wv   = (const float*)d_in[6];
    float* out = (float*)d_out;

    int N = in_sizes[0] / 128;
    int E = in_sizes[2];

    uint2*    featH = (uint2*)d_ws;                      // N*32   (12.8 MB, 256 B/node)
    float4*   pos4  = (float4*)(featH + (size_t)N * 32); // N      (0.8 MB)
    int*      csrP  = (int*)(pos4 + N);                  // N*CAP  (12.8 MB)
    int*      cnt   = csrP + (size_t)N * CAP;            // N      (0.2 MB)
    unsigned* WS2   = (unsigned*)(cnt + N);              // 1024   (4 KB)
    unsigned* WV2   = WS2 + 1024;                        // 1024   (4 KB)

    hipMemsetAsync(cnt, 0, (size_t)N * sizeof(int), stream);

    const int tb = 256;
    int sblocks = (E + tb - 1) / tb;
    int prepTot = N * 32 + N + 1024;
    int pblocks = (prepTot + tb - 1) / tb;
    build_kernel<<<sblocks + pblocks, tb, 0, stream>>>(esrc, edst, feat, pos, Ws, Wv, tpw,
                                                       cnt, csrP, featH, pos4, WS2, WV2,
                                                       N, E, sblocks);
    node_kernel<<<(N + 3) / 4, 256, 0, stream>>>(featH, pos4, csrP, cnt, WS2, WV2, out, N);
}